// Round 14
// baseline (183.372 us; speedup 1.0000x reference)
//
#include <hip/hip_runtime.h>
#include <hip/hip_bf16.h>
#include <hip/hip_cooperative_groups.h>

namespace cg = cooperative_groups;

// LSS voxel pooling, single cooperative kernel:
//  Phase A (264 blocks): ctx transpose->bf16, softmax, LDS bucket-sort,
//    records to deterministic per-tile segments (coalesced) + headers.
//    NO global atomics, no cursor, no memset.
//  grid.sync()
//  Phase B (512 blocks): per (batch,bucket): gather headers, copy runs,
//    in-LDS voxel sort, register accumulate, coalesced out writes.
// Lessons: r1 f32 atomics op-bound; r4 random scatter write-amp; r7 bulk LDS
// atomics serialize; r9/r12/r13 occupancy+traffic all neutral => latency and
// dispatch overhead dominate -> fuse everything, minimize sync points.

constexpr int B = 2, N = 6, D = 112, H = 16, W = 44, C = 80;
constexpr int HW = H * W;          // 704
constexpr int NPIX = B * N * HW;   // 8448
constexpr int NV = 128 * 128;      // 16384
constexpr int DHW = D * HW;        // 78848
constexpr int TPX = 32;            // pixels per scatter tile (704/32=22/cam)
constexpr int NT = NPIX / TPX;     // 264 tiles
constexpr int BT = NT / B;         // 132 tiles per batch
constexpr int TREC = TPX * D;      // 3584 records per tile
constexpr int C2 = C / 2;          // 40 bf16-pairs per pixel
constexpr int GRID = 512;          // == B*256 buckets; co-resident (2/CU)
constexpr int THR = 512;
constexpr int SCAP = 2304;         // per-bucket record cap (mean 1848, +10.6s)

__device__ inline unsigned bf16rne(float f) {
  const unsigned u = __float_as_uint(f);
  return (u + 0x7FFFu + ((u >> 16) & 1u)) >> 16;
}

__global__ __launch_bounds__(THR) void fused_kernel(
    const float* __restrict__ logits, const float* __restrict__ ctx,
    const int* __restrict__ gidx, unsigned* __restrict__ ctxB,
    unsigned* __restrict__ sorted, unsigned* __restrict__ hdr,
    float* __restrict__ out) {
  const int t = threadIdx.x;
  const int blk = blockIdx.x;

  // phase A shared (31.1 KB)
  __shared__ float tile_s[TPX][81];
  __shared__ float redm[TPX][17], reds[TPX][17];
  __shared__ int hist[256], soffA[256];
  __shared__ int wsum[4];
  __shared__ unsigned srecA[TREC];
  // phase B shared (31.0 KB)
  __shared__ int scnt[BT];
  __shared__ unsigned srec2[SCAP];
  __shared__ int shist[64], soff2[64];
  __shared__ float tileO[64][81];

  // ================= Phase A: scatter =================
  if (blk < NT) {
    const int bn = blk / 22;
    const int hw0 = (blk % 22) * TPX;
    const int b = bn / N;
    const int pix0 = bn * HW + hw0;

    if (t < 256) hist[t] = 0;

    // ctx transpose: 32 px x 80 ch staged in LDS
    const float* csrc = ctx + (size_t)bn * C * HW + hw0;
#pragma unroll
    for (int it = 0; it < (TPX * C) / THR; ++it) {  // 5
      const int idx = it * THR + t;
      const int c = idx >> 5;
      const int i = idx & 31;
      tile_s[i][c] = csrc[(size_t)c * HW + i];      // 128B contiguous/32 lanes
    }
    __syncthreads();
    {
      unsigned* dst = ctxB + (size_t)pix0 * C2;
      for (int j = t; j < TPX * C2; j += THR) {     // 1280 u32, coalesced
        const int p = j / C2;
        const int cp = j - p * C2;
        dst[j] = bf16rne(tile_s[p][2 * cp]) |
                 (bf16rne(tile_s[p][2 * cp + 1]) << 16);
      }
    }

    // softmax over D: l=pixel lane (32), q=d-group (16 x 7)
    const int l = t & 31;
    const int q = t >> 5;
    const size_t base = (size_t)bn * DHW + hw0 + l;

    float x[7];
    float m = -3.0e38f;
#pragma unroll
    for (int j = 0; j < 7; ++j) {
      x[j] = logits[base + (size_t)(q * 7 + j) * HW];  // 128B segments
      m = fmaxf(m, x[j]);
    }
    redm[l][q] = m;
    __syncthreads();
#pragma unroll
    for (int qq = 0; qq < 16; ++qq) m = fmaxf(m, redm[l][qq]);
    float s = 0.0f;
#pragma unroll
    for (int j = 0; j < 7; ++j) {
      x[j] = __expf(x[j] - m);
      s += x[j];
    }
    reds[l][q] = s;
    __syncthreads();
    s = 0.0f;
#pragma unroll
    for (int qq = 0; qq < 16; ++qq) s += reds[l][qq];
    const float inv = 1.0f / s;

    // records: vox6 | pix14 | p12; rank via LDS returning-atomic
    unsigned key[7];
    int lb7[7], rank[7];
#pragma unroll
    for (int j = 0; j < 7; ++j) {
      const int fb = b * NV + gidx[base + (size_t)(q * 7 + j) * HW];
      const unsigned p12 = __float2uint_rn(x[j] * inv * 4095.0f);
      key[j] = ((unsigned)(fb & 63) << 26) | ((unsigned)(pix0 + l) << 12) | p12;
      lb7[j] = (fb >> 6) & 255;
      rank[j] = atomicAdd(&hist[lb7[j]], 1);
    }
    __syncthreads();

    // exclusive scan over 256 bins (4-wave shfl scan)
    const int hv = (t < 256) ? hist[t] : 0;
    int xx = hv;
#pragma unroll
    for (int o = 1; o < 64; o <<= 1) {
      const int y = __shfl_up(xx, o, 64);
      if ((t & 63) >= o) xx += y;
    }
    if (((t & 63) == 63) && t < 256) wsum[t >> 6] = xx;
    __syncthreads();
    if (t < 256) {
      int woff = 0;
#pragma unroll
      for (int ww = 0; ww < 4; ++ww)
        if (ww < (t >> 6)) woff += wsum[ww];
      soffA[t] = woff + xx - hv;
    }
    __syncthreads();

    // place bucket-sorted in LDS; write headers
#pragma unroll
    for (int j = 0; j < 7; ++j)
      srecA[soffA[lb7[j]] + rank[j]] = key[j];
    if (t < 256)
      hdr[(size_t)blk * 256 + t] =
          ((unsigned)soffA[t] << 16) | (unsigned)hist[t];
    __syncthreads();

    // dump: fully coalesced 2KB stores into this tile's own segment
    for (int s_ = t; s_ < TREC; s_ += THR)
      sorted[(size_t)blk * TREC + s_] = srecA[s_];
  }

  cg::this_grid().sync();

  // ================= Phase B: gather =================
  const int b = blk >> 8;
  const int lb = blk & 255;

  if (t < 64) shist[t] = 0;
  int cnt_t = 0, off_t = 0;
  if (t < BT) {
    const unsigned h = hdr[(size_t)(b * BT + t) * 256 + lb];  // 1 gather instr
    off_t = (int)(h >> 16);
    cnt_t = (int)(h & 0xFFFFu);
    scnt[t] = cnt_t;
  }
  __syncthreads();
  // Hillis-Steele inclusive scan over 132 counts
  for (int o = 1; o < BT; o <<= 1) {
    const int v = (t >= o && t < BT) ? scnt[t - o] : 0;
    __syncthreads();
    if (t < BT) scnt[t] += v;
    __syncthreads();
  }
  int total = scnt[BT - 1];
  if (total > SCAP) total = SCAP;
  // copy this bucket's runs from 132 tile segments into LDS
  if (t < BT) {
    const int pos = scnt[t] - cnt_t;
    const unsigned* src = sorted + (size_t)(b * BT + t) * TREC + off_t;
    for (int i = 0; i < cnt_t; ++i) {
      const int p = pos + i;
      if (p < SCAP) srec2[p] = src[i];
    }
  }
  __syncthreads();

  // voxel histogram + rank (records held in registers)
  unsigned rr[5];
  int rk[5];
#pragma unroll
  for (int k = 0; k < 5; ++k) {
    const int idx = t + k * THR;
    rk[k] = -1;
    if (idx < total) {
      rr[k] = srec2[idx];
      rk[k] = atomicAdd(&shist[rr[k] >> 26], 1);
    }
  }
  __syncthreads();
  if (t < 64) {
    const int v = shist[t];
    int xx = v;
#pragma unroll
    for (int o = 1; o < 64; o <<= 1) {
      const int y = __shfl_up(xx, o, 64);
      if (t >= o) xx += y;
    }
    soff2[t] = xx - v;
  }
  __syncthreads();
#pragma unroll
  for (int k = 0; k < 5; ++k)
    if (rk[k] >= 0) srec2[soff2[rr[k] >> 26] + rk[k]] = rr[k];
  __syncthreads();

  // register accumulation: 8 waves x 8 voxels; lane l<40 owns ch 2l,2l+1
  constexpr float QS = 1.0f / 4095.0f;
  const int w = t >> 6;
  const int l = t & 63;
  for (int j = 0; j < 8; ++j) {
    const int v = w * 8 + j;
    const int s0 = soff2[v];
    const int n = shist[v];
    float a0 = 0.0f, a1 = 0.0f;
    int k = 0;
    for (; k + 4 <= n; k += 4) {
      const unsigned ra = srec2[s0 + k + 0];  // broadcast ds_read
      const unsigned rb = srec2[s0 + k + 1];
      const unsigned rc = srec2[s0 + k + 2];
      const unsigned rd = srec2[s0 + k + 3];
      if (l < C2) {
        const unsigned ua = ctxB[(size_t)((ra >> 12) & 0x3FFFu) * C2 + l];
        const unsigned ub = ctxB[(size_t)((rb >> 12) & 0x3FFFu) * C2 + l];
        const unsigned uc = ctxB[(size_t)((rc >> 12) & 0x3FFFu) * C2 + l];
        const unsigned ud = ctxB[(size_t)((rd >> 12) & 0x3FFFu) * C2 + l];
        const float pa = (float)(ra & 0xFFFu) * QS;
        const float pb = (float)(rb & 0xFFFu) * QS;
        const float pc = (float)(rc & 0xFFFu) * QS;
        const float pd = (float)(rd & 0xFFFu) * QS;
        a0 += pa * __uint_as_float(ua << 16);
        a1 += pa * __uint_as_float(ua & 0xFFFF0000u);
        a0 += pb * __uint_as_float(ub << 16);
        a1 += pb * __uint_as_float(ub & 0xFFFF0000u);
        a0 += pc * __uint_as_float(uc << 16);
        a1 += pc * __uint_as_float(uc & 0xFFFF0000u);
        a0 += pd * __uint_as_float(ud << 16);
        a1 += pd * __uint_as_float(ud & 0xFFFF0000u);
      }
    }
    for (; k < n; ++k) {
      const unsigned ra = srec2[s0 + k];
      if (l < C2) {
        const unsigned ua = ctxB[(size_t)((ra >> 12) & 0x3FFFu) * C2 + l];
        const float pa = (float)(ra & 0xFFFu) * QS;
        a0 += pa * __uint_as_float(ua << 16);
        a1 += pa * __uint_as_float(ua & 0xFFFF0000u);
      }
    }
    if (l < C2) {
      tileO[v][2 * l] = a0;
      tileO[v][2 * l + 1] = a1;
    }
  }
  __syncthreads();

  // coalesced out write [b][c][lb*64 .. +64)
  const size_t ob = (size_t)b * C * NV + (size_t)lb * 64;
#pragma unroll
  for (int i = 0; i < 10; ++i) {
    const int idx = i * THR + t;
    const int c = idx >> 6;
    const int v = idx & 63;
    out[ob + (size_t)c * NV + v] = tileO[v][c];
  }
}

// ---- fallback: direct channel-major atomics (out must be zeroed) ----
__global__ __launch_bounds__(256) void lift_splat_direct_kernel(
    const float* __restrict__ logits, const float* __restrict__ ctx,
    const int* __restrict__ gidx, float* __restrict__ out) {
  const int t = threadIdx.x;
  const int pix = blockIdx.x;
  const int hw = pix % HW;
  const int bn = pix / HW;
  const int b = bn / N;

  const float* lg = logits + (size_t)bn * DHW + hw;
  const int* gi = gidx + (size_t)bn * DHW + hw;
  const float* cx = ctx + (size_t)bn * (C * HW) + hw;

  __shared__ float s_prob[D];
  __shared__ float s_ctx[C];
  __shared__ int s_idx[D];
  __shared__ float red[256];

  float v = -3.0e38f;
  if (t < D) {
    v = lg[(size_t)t * HW];
    s_idx[t] = gi[(size_t)t * HW];
  }
  if (t < C) s_ctx[t] = cx[(size_t)t * HW];

  red[t] = v;
  __syncthreads();
#pragma unroll
  for (int s = 128; s >= 1; s >>= 1) {
    if (t < s) red[t] = fmaxf(red[t], red[t + s]);
    __syncthreads();
  }
  const float m = red[0];
  __syncthreads();

  const float e = (t < D) ? __expf(v - m) : 0.0f;
  red[t] = e;
  __syncthreads();
#pragma unroll
  for (int s = 128; s >= 1; s >>= 1) {
    if (t < s) red[t] += red[t + s];
    __syncthreads();
  }
  const float inv = 1.0f / red[0];
  if (t < D) s_prob[t] = e * inv;
  __syncthreads();

  for (int f = t; f < D * C; f += 256) {
    const int d = f / C;
    const int c = f - d * C;
    atomicAdd(&out[((size_t)(b * C + c)) * NV + s_idx[d]],
              s_prob[d] * s_ctx[c]);
  }
}

extern "C" void kernel_launch(void* const* d_in, const int* in_sizes, int n_in,
                              void* d_out, int out_size, void* d_ws,
                              size_t ws_size, hipStream_t stream) {
  const float* logits = (const float*)d_in[0];
  const float* ctx = (const float*)d_in[1];
  const int* gidx = (const int*)d_in[2];
  float* out = (float*)d_out;

  size_t off = 0;
  unsigned* sorted = (unsigned*)((char*)d_ws + off);
  off += (size_t)NT * TREC * sizeof(unsigned);           // 3,784,704
  unsigned* ctxB = (unsigned*)((char*)d_ws + off);
  off += (size_t)NPIX * C2 * sizeof(unsigned);           // 1,351,680
  unsigned* hdr = (unsigned*)((char*)d_ws + off);
  off += (size_t)NT * 256 * sizeof(unsigned);            //   270,336

  if (ws_size >= off) {
    void* kargs[7];
    kargs[0] = (void*)&logits;
    kargs[1] = (void*)&ctx;
    kargs[2] = (void*)&gidx;
    kargs[3] = (void*)&ctxB;
    kargs[4] = (void*)&sorted;
    kargs[5] = (void*)&hdr;
    kargs[6] = (void*)&out;
    (void)hipLaunchCooperativeKernel(
        reinterpret_cast<void*>(fused_kernel), dim3(GRID), dim3(THR), kargs,
        0, stream);
  } else {
    (void)hipMemsetAsync(d_out, 0, (size_t)out_size * sizeof(float), stream);
    lift_splat_direct_kernel<<<NPIX, 256, 0, stream>>>(logits, ctx, gidx, out);
  }
}

// Round 15
// 125.773 us; speedup vs baseline: 1.4580x; 1.4580x over previous
//
#include <hip/hip_runtime.h>
#include <hip/hip_bf16.h>

// LSS voxel pooling (r13 pipeline, gather launched 2x as a timing probe):
// fused {ctx-transpose(bf16) + softmax + LDS-sorted 512-bucket scatter} ->
// {in-LDS voxel sort + register-accumulate gather}.
// gather is idempotent => double launch is correct; dur_us - 102.4 = G.
// Lessons: r1 f32 atomics op-bound; r4 random scatter write-amp; r7 bulk LDS
// atomics serialize; r9/r12/r13 occupancy+traffic neutral; r14 coop fusion
// lost 2x (bad phase shaping) but proved latency-bound (VALU 19%, HBM 4%).

constexpr int B = 2, N = 6, D = 112, H = 16, W = 44, C = 80;
constexpr int HW = H * W;            // 704
constexpr int NPIX = B * N * HW;     // 8448
constexpr int NV = 128 * 128;        // 16384
constexpr int DHW = D * HW;          // 78848
constexpr int NBKT = 512;            // global buckets (64 voxel-bins each)
constexpr int CAP = 2816;            // per-bucket capacity (mean 1848, +22 sigma)
constexpr int RPB = 16 * D;          // records per scatter block = 1792
constexpr int C2 = C / 2;            // 40 bf16-pairs per pixel row

__device__ inline unsigned bf16rne(float f) {
  const unsigned u = __float_as_uint(f);
  return (u + 0x7FFFu + ((u >> 16) & 1u)) >> 16;
}

// ---- pass 1: fused ctx transpose(->bf16) + softmax + bucketed scatter ----
__global__ __launch_bounds__(256) void scatter_kernel(
    const float* __restrict__ logits, const float* __restrict__ ctx,
    const int* __restrict__ gidx, unsigned* __restrict__ ctxB,
    int* __restrict__ cursor, unsigned* __restrict__ sorted) {
  const int t = threadIdx.x;
  const int blk = blockIdx.x;        // bn * 44 + chunk
  const int bn = blk / 44;
  const int hw0 = (blk - bn * 44) * 16;
  const int b = bn / N;
  const int pix0 = bn * HW + hw0;

  __shared__ float tile[16][81];
  __shared__ float redm[16][17], reds[16][17];
  __shared__ int hist[256], sbase[256], soff[256];
  __shared__ int wsum[4];
  __shared__ unsigned srec[RPB];
  __shared__ unsigned char sbkt[RPB];

  hist[t] = 0;

  // --- ctx transpose: 16 pixels x 80 ch, pack to bf16 pairs ---
  const float* csrc = ctx + (size_t)bn * C * HW + hw0;
#pragma unroll
  for (int it = 0; it < (16 * C) / 256; ++it) {
    const int idx = it * 256 + t;
    const int c = idx >> 4;
    const int i = idx & 15;
    tile[i][c] = csrc[(size_t)c * HW + i];
  }
  __syncthreads();
  {
    unsigned* dst = ctxB + (size_t)pix0 * C2;
    for (int j = t; j < 16 * C2; j += 256) {
      const int p = j / C2;
      const int cp = j - p * C2;
      dst[j] = bf16rne(tile[p][2 * cp]) |
               (bf16rne(tile[p][2 * cp + 1]) << 16);
    }
  }

  // --- softmax over D: 7 logits/thread, 16-group reduce per pixel ---
  const int l = t & 15;
  const int q = t >> 4;
  const size_t base = (size_t)bn * DHW + hw0 + l;

  float x[7];
  float m = -3.0e38f;
#pragma unroll
  for (int j = 0; j < 7; ++j) {
    x[j] = logits[base + (size_t)(q * 7 + j) * HW];
    m = fmaxf(m, x[j]);
  }
  redm[l][q] = m;
  __syncthreads();
#pragma unroll
  for (int qq = 0; qq < 16; ++qq) m = fmaxf(m, redm[l][qq]);
  float s = 0.0f;
#pragma unroll
  for (int j = 0; j < 7; ++j) {
    x[j] = __expf(x[j] - m);
    s += x[j];
  }
  reds[l][q] = s;
  __syncthreads();
  s = 0.0f;
#pragma unroll
  for (int qq = 0; qq < 16; ++qq) s += reds[l][qq];
  const float inv = 1.0f / s;

  // --- 4B records + block-local rank ---
  unsigned key[7];
  int lb7[7], rank[7];
#pragma unroll
  for (int j = 0; j < 7; ++j) {
    const int fb = b * NV + gidx[base + (size_t)(q * 7 + j) * HW];
    const unsigned p12 = __float2uint_rn(x[j] * inv * 4095.0f);
    key[j] = ((unsigned)(fb & 63) << 26) | ((unsigned)(pix0 + l) << 12) | p12;
    lb7[j] = (fb >> 6) & 255;
    rank[j] = atomicAdd(&hist[lb7[j]], 1);
  }
  __syncthreads();

  // --- exclusive scan over 256 bins + global range reservation ---
  const int hv = hist[t];
  int xx = hv;
#pragma unroll
  for (int o = 1; o < 64; o <<= 1) {
    const int y = __shfl_up(xx, o, 64);
    if ((t & 63) >= o) xx += y;
  }
  if ((t & 63) == 63) wsum[t >> 6] = xx;
  sbase[t] = hv ? atomicAdd(&cursor[(b << 8) | t], hv) : 0;
  __syncthreads();
  int woff = 0;
#pragma unroll
  for (int ww = 0; ww < 4; ++ww)
    if (ww < (t >> 6)) woff += wsum[ww];
  soff[t] = woff + xx - hv;
  __syncthreads();

  // --- place records bucket-sorted in LDS ---
#pragma unroll
  for (int j = 0; j < 7; ++j) {
    const int slot = soff[lb7[j]] + rank[j];
    srec[slot] = key[j];
    sbkt[slot] = (unsigned char)lb7[j];
  }
  __syncthreads();

  // --- dump: consecutive slots = same-bucket runs -> clustered stores ---
  for (int s_ = t; s_ < RPB; s_ += 256) {
    const int lb = sbkt[s_];
    const int posin = sbase[lb] + (s_ - soff[lb]);
    if (posin < CAP)                 // statistically unreachable guard
      sorted[(size_t)((b << 8) | lb) * CAP + posin] = srec[s_];
  }
}

// ---- pass 2: bucket gather (idempotent; launched twice as probe) ----
__global__ __launch_bounds__(1024) void gather_kernel(
    const unsigned* __restrict__ ctxB, const unsigned* __restrict__ sorted,
    const int* __restrict__ cursor, float* __restrict__ out) {
  const int t = threadIdx.x;
  const int g = blockIdx.x;
  const int b = g >> 8;
  const int vox0 = (g & 255) * 64;

  __shared__ unsigned srec[CAP];
  __shared__ float tile[64][80];
  __shared__ int shist[64], soff[64];

  if (t < 64) shist[t] = 0;
  __syncthreads();

  int cnt = cursor[g];
  if (cnt > CAP) cnt = CAP;
  const unsigned* rec = sorted + (size_t)g * CAP;

  unsigned rr[3];
  int rk[3];
#pragma unroll
  for (int k = 0; k < 3; ++k) {
    const int idx = t + k * 1024;
    rk[k] = -1;
    if (idx < cnt) {
      rr[k] = rec[idx];
      rk[k] = atomicAdd(&shist[rr[k] >> 26], 1);
    }
  }
  __syncthreads();

  if (t < 64) {
    const int v = shist[t];
    int xx = v;
#pragma unroll
    for (int o = 1; o < 64; o <<= 1) {
      const int y = __shfl_up(xx, o, 64);
      if (t >= o) xx += y;
    }
    soff[t] = xx - v;
  }
  __syncthreads();

#pragma unroll
  for (int k = 0; k < 3; ++k) {
    if (rk[k] >= 0) srec[soff[rr[k] >> 26] + rk[k]] = rr[k];
  }
  __syncthreads();

  constexpr float QS = 1.0f / 4095.0f;
  const int w = t >> 6;
  const int l = t & 63;
  for (int j = 0; j < 4; ++j) {
    const int v = w * 4 + j;
    const int s0 = soff[v];
    const int n = shist[v];
    float a0 = 0.0f, a1 = 0.0f;
    int k = 0;
    for (; k + 4 <= n; k += 4) {
      const unsigned ra = srec[s0 + k + 0];
      const unsigned rb = srec[s0 + k + 1];
      const unsigned rc = srec[s0 + k + 2];
      const unsigned rd = srec[s0 + k + 3];
      if (l < C2) {
        const unsigned ua = ctxB[(size_t)((ra >> 12) & 0x3FFFu) * C2 + l];
        const unsigned ub = ctxB[(size_t)((rb >> 12) & 0x3FFFu) * C2 + l];
        const unsigned uc = ctxB[(size_t)((rc >> 12) & 0x3FFFu) * C2 + l];
        const unsigned ud = ctxB[(size_t)((rd >> 12) & 0x3FFFu) * C2 + l];
        const float pa = (float)(ra & 0xFFFu) * QS;
        const float pb = (float)(rb & 0xFFFu) * QS;
        const float pc = (float)(rc & 0xFFFu) * QS;
        const float pd = (float)(rd & 0xFFFu) * QS;
        a0 += pa * __uint_as_float(ua << 16);
        a1 += pa * __uint_as_float(ua & 0xFFFF0000u);
        a0 += pb * __uint_as_float(ub << 16);
        a1 += pb * __uint_as_float(ub & 0xFFFF0000u);
        a0 += pc * __uint_as_float(uc << 16);
        a1 += pc * __uint_as_float(uc & 0xFFFF0000u);
        a0 += pd * __uint_as_float(ud << 16);
        a1 += pd * __uint_as_float(ud & 0xFFFF0000u);
      }
    }
    for (; k < n; ++k) {
      const unsigned ra = srec[s0 + k];
      if (l < C2) {
        const unsigned ua = ctxB[(size_t)((ra >> 12) & 0x3FFFu) * C2 + l];
        const float pa = (float)(ra & 0xFFFu) * QS;
        a0 += pa * __uint_as_float(ua << 16);
        a1 += pa * __uint_as_float(ua & 0xFFFF0000u);
      }
    }
    if (l < C2) {
      tile[v][2 * l] = a0;
      tile[v][2 * l + 1] = a1;
    }
  }
  __syncthreads();

  const size_t ob = (size_t)b * C * NV + vox0;
#pragma unroll
  for (int i = 0; i < 5; ++i) {
    const int idx = i * 1024 + t;
    const int c = idx >> 6;
    const int v = idx & 63;
    out[ob + (size_t)c * NV + v] = tile[v][c];
  }
}

// ---- fallback: direct channel-major atomics (out must be zeroed) ----
__global__ __launch_bounds__(256) void lift_splat_direct_kernel(
    const float* __restrict__ logits, const float* __restrict__ ctx,
    const int* __restrict__ gidx, float* __restrict__ out) {
  const int t = threadIdx.x;
  const int pix = blockIdx.x;
  const int hw = pix % HW;
  const int bn = pix / HW;
  const int b = bn / N;

  const float* lg = logits + (size_t)bn * DHW + hw;
  const int* gi = gidx + (size_t)bn * DHW + hw;
  const float* cx = ctx + (size_t)bn * (C * HW) + hw;

  __shared__ float s_prob[D];
  __shared__ float s_ctx[C];
  __shared__ int s_idx[D];
  __shared__ float red[256];

  float v = -3.0e38f;
  if (t < D) {
    v = lg[(size_t)t * HW];
    s_idx[t] = gi[(size_t)t * HW];
  }
  if (t < C) s_ctx[t] = cx[(size_t)t * HW];

  red[t] = v;
  __syncthreads();
#pragma unroll
  for (int s = 128; s >= 1; s >>= 1) {
    if (t < s) red[t] = fmaxf(red[t], red[t + s]);
    __syncthreads();
  }
  const float m = red[0];
  __syncthreads();

  const float e = (t < D) ? __expf(v - m) : 0.0f;
  red[t] = e;
  __syncthreads();
#pragma unroll
  for (int s = 128; s >= 1; s >>= 1) {
    if (t < s) red[t] += red[t + s];
    __syncthreads();
  }
  const float inv = 1.0f / red[0];
  if (t < D) s_prob[t] = e * inv;
  __syncthreads();

  for (int f = t; f < D * C; f += 256) {
    const int d = f / C;
    const int c = f - d * C;
    atomicAdd(&out[((size_t)(b * C + c)) * NV + s_idx[d]],
              s_prob[d] * s_ctx[c]);
  }
}

extern "C" void kernel_launch(void* const* d_in, const int* in_sizes, int n_in,
                              void* d_out, int out_size, void* d_ws,
                              size_t ws_size, hipStream_t stream) {
  const float* logits = (const float*)d_in[0];
  const float* ctx = (const float*)d_in[1];
  const int* gidx = (const int*)d_in[2];
  float* out = (float*)d_out;

  size_t off = 0;
  unsigned* sorted = (unsigned*)((char*)d_ws + off);
  off += (size_t)NBKT * CAP * sizeof(unsigned);
  unsigned* ctxB = (unsigned*)((char*)d_ws + off);
  off += (size_t)NPIX * C2 * sizeof(unsigned);
  int* cursor = (int*)((char*)d_ws + off);
  off += (size_t)NBKT * sizeof(int);

  if (ws_size >= off) {
    (void)hipMemsetAsync(cursor, 0, (size_t)NBKT * sizeof(int), stream);
    scatter_kernel<<<B * N * (HW / 16), 256, 0, stream>>>(
        logits, ctx, gidx, ctxB, cursor, sorted);
    // PROBE: gather launched twice (idempotent). dur_us - baseline == G.
    gather_kernel<<<NBKT, 1024, 0, stream>>>(ctxB, sorted, cursor, out);
    gather_kernel<<<NBKT, 1024, 0, stream>>>(ctxB, sorted, cursor, out);
  } else {
    (void)hipMemsetAsync(d_out, 0, (size_t)out_size * sizeof(float), stream);
    lift_splat_direct_kernel<<<NPIX, 256, 0, stream>>>(logits, ctx, gidx, out);
  }
}